// Round 1
// baseline (229.793 us; speedup 1.0000x reference)
//
#include <hip/hip_runtime.h>
#include <hip/hip_bf16.h>
#include <hip/hip_fp16.h>
#include <math.h>

#define B_  8
#define N_  1025
#define C_  512
#define H_  8
#define HD_ 64
#define M_  (B_ * N_)   // 8200
#define VCS 2560        // shorts per vtc chunk-block: 64 dims * 40 (32 keys + 8 pad)
#define VST 36          // vtc chunk-blocks per bh (33 used)

typedef __attribute__((ext_vector_type(8))) short short8;
typedef __attribute__((ext_vector_type(4))) float f32x4;

__device__ inline unsigned short bf16u(float x) {
    __hip_bfloat16 t = __float2bfloat16(x);
    return *(unsigned short*)&t;
}
__device__ inline float fexp2(float x) {   // 2^x via v_exp_f32
    float r;
    asm("v_exp_f32 %0, %1" : "=v"(r) : "v"(x));
    return r;
}
__device__ inline void load_lds16(const void* g, void* l) {
    __builtin_amdgcn_global_load_lds(
        (const __attribute__((address_space(1))) unsigned int*)g,
        (__attribute__((address_space(3))) unsigned int*)l, 16, 0, 0);
}

// ---------------------------------------------------------------------------
// Fused prep: blocks 0..31 build the H x 32 x 32 table (now in LOG2 so attn
// can use raw v_exp_f32); rest cast to bf16.
// ---------------------------------------------------------------------------
#define PER_ ((size_t)B_ * H_ * N_ * HD_)      // 4,198,400
#define SZ_QKVW (3 * C_ * C_)
#define SZ_PRJW (C_ * C_)
#define CAST_BLKS ((4198400 + 786432 + 262144) / 4 / 256)   // 5124

__global__ void prep_kernel(const float* __restrict__ x,
                            const float* __restrict__ qkv_w,
                            const float* __restrict__ proj_w,
                            const float* __restrict__ wg_w,
                            const float* __restrict__ wg_b,
                            unsigned short* __restrict__ xb,
                            unsigned short* __restrict__ wqkvb,
                            unsigned short* __restrict__ wprjb,
                            float* __restrict__ tab) {
    int blk = blockIdx.x;
    int tid = threadIdx.x;
    if (blk < 32) {
        int idx = blk * 256 + tid;
        int h = idx >> 10;
        int a = (idx >> 5) & 31;
        int b = idx & 31;
        float dx = logf(fmaxf((float)a * (1.0f / 33.0f), 0.001f));
        float dy = logf(fmaxf((float)b * (1.0f / 33.0f), 0.001f));
        const float* w = wg_w + h * 64;
        float acc = wg_b[h];
#pragma unroll
        for (int k = 0; k < 8; k++) {
            float f = powf(1000.0f, -(float)k * 0.125f);
            float X = 100.0f * dx * f;
            float Y = 100.0f * dy * f;
            acc += w[k]      * sinf(X);
            acc += w[8 + k]  * sinf(Y);
            acc += w[32 + k] * cosf(X);
            acc += w[40 + k] * cosf(Y);
            acc += w[48 + k] + w[56 + k];
        }
        tab[idx] = log2f(fmaxf(fmaxf(acc, 0.0f), 1e-6f));   // log2 now
        return;
    }
    long i4 = ((long)(blk - 32) * 256 + tid) * 4;
    const float* src;
    unsigned short* dst;
    long off;
    if (i4 < (long)PER_)                    { src = x;      dst = xb;    off = i4; }
    else if (i4 < (long)PER_ + SZ_QKVW)     { src = qkv_w;  dst = wqkvb; off = i4 - PER_; }
    else                                    { src = proj_w; dst = wprjb; off = i4 - PER_ - SZ_QKVW; }
    float4 v = *(const float4*)(src + off);
    ushort4 p;
    p.x = bf16u(v.x); p.y = bf16u(v.y); p.z = bf16u(v.z); p.w = bf16u(v.w);
    *(ushort4*)(dst + off) = p;
}

// ---------------------------------------------------------------------------
// Expanded bias table: bigtab[h][r 0..1151][c 0..1055] fp16, log2-scaled.
//   r==0 or c==0 -> 0 (the jnp.pad row/col); c>1024 -> -60000 (exp2 -> 0,
//   removes the col-OOB cndmask in attn); r>=1025 -> clamped (finite, rows
//   are compute-only pad whose stores are skipped).
// ---------------------------------------------------------------------------
__global__ __launch_bounds__(256) void bias_expand(const float* __restrict__ tab,
                                                   unsigned short* __restrict__ big) {
    int idx = blockIdx.x * 256 + threadIdx.x;   // 1,216,512 threads, 8 cols each
    int cw = idx % 132;
    int rh = idx / 132;
    int r  = rh % 1152;
    int h  = rh / 1152;
    int c0 = cw * 8;
    int i  = min(r, 1024) - 1;                  // valid when r>=1
    int ix = i >> 5, iy = i & 31;
    const float* th = tab + h * 1024;
    unsigned short o8[8];
#pragma unroll
    for (int e = 0; e < 8; e++) {
        int c = c0 + e;
        float v;
        if (r == 0 || c == 0) v = 0.f;
        else if (c > 1024)    v = -60000.f;
        else {
            int j = c - 1;
            int da = __sad(ix, j >> 5, 0u);
            int db = __sad(iy, j & 31, 0u);
            v = th[da * 32 + db];
        }
        __half hv = __float2half(v);
        o8[e] = *(unsigned short*)&hv;
    }
    *(short8*)(big + (size_t)rh * 1056 + c0) = *(short8*)o8;
}

// ---------------------------------------------------------------------------
// MFMA GEMM, 128x128 tile, BK=32, 4 waves, unified swapped-operand MFMA.
// q scaled by 0.125*log2(e) (exp2 folding). v stored to vtc with key-slot
// permutation sigma(k)=((k&15)<<1)|(k>>4) and 40-stride dim rows (8-slot pad
// per 32 keys) so the attn LDS image is bank-conflict-free verbatim.
// ---------------------------------------------------------------------------
#define GK 512

__global__ __launch_bounds__(256) void gemm_qkv_mfma(
        const unsigned short* __restrict__ A, const unsigned short* __restrict__ W,
        unsigned short* __restrict__ qb, unsigned short* __restrict__ kb,
        unsigned short* __restrict__ vtc) {
    __shared__ __align__(16) unsigned short As[128 * 32];
    __shared__ __align__(16) unsigned short Bs[128 * 32];
    int tid = threadIdx.x;
    int w = tid >> 6, lane = tid & 63;
    int quad = lane >> 4, l16 = lane & 15;
    int m0 = blockIdx.y * 128;
    int n0 = blockIdx.x * 128;
    int wr = (w >> 1) * 64, wc = (w & 1) * 64;

    int c0 = tid, c1 = tid + 256;
    int a_r0 = min(m0 + (c0 >> 2), M_ - 1), a_c0 = (c0 & 3) * 8;
    int a_r1 = min(m0 + (c1 >> 2), M_ - 1), a_c1 = (c1 & 3) * 8;
    int b_r0 = n0 + (c0 >> 2), b_r1 = n0 + (c1 >> 2);

    int which = n0 >> 9;                       // 0=q 1=k 2=v
    int h = ((n0 + wc) >> 6) & 7;

    f32x4 acc[4][4];
    const f32x4 zero4 = {0.f, 0.f, 0.f, 0.f};
#pragma unroll
    for (int mi = 0; mi < 4; mi++)
#pragma unroll
        for (int ni = 0; ni < 4; ni++) acc[mi][ni] = zero4;

    for (int k0 = 0; k0 < GK; k0 += 32) {
        __syncthreads();
        load_lds16(A + (size_t)a_r0 * GK + k0 + a_c0, &As[w * 512]);
        load_lds16(A + (size_t)a_r1 * GK + k0 + a_c1, &As[2048 + w * 512]);
        load_lds16(W + (size_t)b_r0 * GK + k0 + a_c0, &Bs[w * 512]);
        load_lds16(W + (size_t)b_r1 * GK + k0 + a_c1, &Bs[2048 + w * 512]);
        __syncthreads();
        short8 af[4], bf[4];
#pragma unroll
        for (int mi = 0; mi < 4; mi++)
            af[mi] = *(const short8*)&As[(wr + mi * 16 + l16) * 32 + quad * 8];
#pragma unroll
        for (int ni = 0; ni < 4; ni++)
            bf[ni] = *(const short8*)&Bs[(wc + ni * 16 + l16) * 32 + quad * 8];
#pragma unroll
        for (int mi = 0; mi < 4; mi++)
#pragma unroll
            for (int ni = 0; ni < 4; ni++)
                acc[mi][ni] = __builtin_amdgcn_mfma_f32_16x16x32_bf16(
                    bf[ni], af[mi], acc[mi][ni], 0, 0, 0);
    }

    if (which < 2) {
        unsigned short* dst = (which == 0) ? qb : kb;
        float sc = (which == 0) ? 0.18033688f : 1.0f;   // 0.125 * log2(e)
#pragma unroll
        for (int mi = 0; mi < 4; mi++) {
            int m = m0 + wr + mi * 16 + l16;
            if (m < M_) {
                int bb = m / N_;
                int i  = m - bb * N_;
                unsigned short* row = dst + ((size_t)(bb * H_ + h) * N_ + i) * HD_;
#pragma unroll
                for (int ni = 0; ni < 4; ni++) {
                    ushort4 pk;
                    pk.x = bf16u(acc[mi][ni][0] * sc);
                    pk.y = bf16u(acc[mi][ni][1] * sc);
                    pk.z = bf16u(acc[mi][ni][2] * sc);
                    pk.w = bf16u(acc[mi][ni][3] * sc);
                    *(ushort4*)(row + ni * 16 + quad * 4) = pk;
                }
            }
        }
    } else {
#pragma unroll
        for (int mi = 0; mi < 4; mi++) {
            int m = m0 + wr + mi * 16 + l16;
            if (m < M_) {
                int bb = m / N_;
                int i  = m - bb * N_;
                int ch = i >> 5, key = i & 31;
                int slot = ((key & 15) << 1) | (key >> 4);   // sigma(key)
                unsigned short* base = vtc + ((size_t)(bb * H_ + h) * VST + ch) * VCS + slot;
#pragma unroll
                for (int ni = 0; ni < 4; ni++)
#pragma unroll
                    for (int reg = 0; reg < 4; reg++)
                        base[(ni * 16 + quad * 4 + reg) * 40] = bf16u(acc[mi][ni][reg]);
            }
        }
    }
}

__global__ __launch_bounds__(256) void gemm_proj_mfma(
        const unsigned short* __restrict__ A, const unsigned short* __restrict__ W,
        const float* __restrict__ bias, float* __restrict__ out) {
    __shared__ __align__(16) unsigned short As[128 * 32];
    __shared__ __align__(16) unsigned short Bs[128 * 32];
    int tid = threadIdx.x;
    int w = tid >> 6, lane = tid & 63;
    int quad = lane >> 4, l16 = lane & 15;
    int m0 = blockIdx.y * 128;
    int n0 = blockIdx.x * 128;
    int wr = (w >> 1) * 64, wc = (w & 1) * 64;

    int c0 = tid, c1 = tid + 256;
    int a_r0 = min(m0 + (c0 >> 2), M_ - 1), a_c0 = (c0 & 3) * 8;
    int a_r1 = min(m0 + (c1 >> 2), M_ - 1), a_c1 = (c1 & 3) * 8;
    int b_r0 = n0 + (c0 >> 2), b_r1 = n0 + (c1 >> 2);

    f32x4 acc[4][4];
    const f32x4 zero4 = {0.f, 0.f, 0.f, 0.f};
#pragma unroll
    for (int mi = 0; mi < 4; mi++)
#pragma unroll
        for (int ni = 0; ni < 4; ni++) acc[mi][ni] = zero4;

    for (int k0 = 0; k0 < GK; k0 += 32) {
        __syncthreads();
        load_lds16(A + (size_t)a_r0 * GK + k0 + a_c0, &As[w * 512]);
        load_lds16(A + (size_t)a_r1 * GK + k0 + a_c1, &As[2048 + w * 512]);
        load_lds16(W + (size_t)b_r0 * GK + k0 + a_c0, &Bs[w * 512]);
        load_lds16(W + (size_t)b_r1 * GK + k0 + a_c1, &Bs[2048 + w * 512]);
        __syncthreads();
        short8 af[4], bf[4];
#pragma unroll
        for (int mi = 0; mi < 4; mi++)
            af[mi] = *(const short8*)&As[(wr + mi * 16 + l16) * 32 + quad * 8];
#pragma unroll
        for (int ni = 0; ni < 4; ni++)
            bf[ni] = *(const short8*)&Bs[(wc + ni * 16 + l16) * 32 + quad * 8];
#pragma unroll
        for (int mi = 0; mi < 4; mi++)
#pragma unroll
            for (int ni = 0; ni < 4; ni++)
                acc[mi][ni] = __builtin_amdgcn_mfma_f32_16x16x32_bf16(
                    af[mi], bf[ni], acc[mi][ni], 0, 0, 0);
    }

    float bvals[4];
#pragma unroll
    for (int ni = 0; ni < 4; ni++) bvals[ni] = bias[n0 + wc + ni * 16 + l16];
#pragma unroll
    for (int mi = 0; mi < 4; mi++)
#pragma unroll
        for (int reg = 0; reg < 4; reg++) {
            int m = m0 + wr + mi * 16 + quad * 4 + reg;
            if (m < M_) {
                float* row = out + (size_t)m * C_ + n0 + wc;
#pragma unroll
                for (int ni = 0; ni < 4; ni++)
                    row[ni * 16 + l16] = acc[mi][ni][reg] + bvals[ni];
            }
        }
}

// ---------------------------------------------------------------------------
// FUSED attention v6: counters said LDS-serialized (Vs 8-way conflicts) +
// VALU-heavy softmax. Changes vs v5:
//  (1) Vs dim rows stride 40 (pad baked into the vtc GLOBAL layout so verbatim
//      global_load_lds staging stays legal) -> granule (5*l16+quad)%8 covers
//      all 8 LDS 16B-granules evenly: Vs/Pw/Ks reads all conflict-free.
//  (2) bias from precomputed fp16 bigtab (log2-scaled, pad row/col + col-OOB
//      -60000 baked in): per element = load+cvt+add+v_exp_f32+pack. Loads are
//      issued before stage() so the compiler's counted vmcnt leaves the K/V
//      prefetch in flight.
//  (3) P key axis permuted sigma(k)=((k&15)<<1)|(k>>4) in BOTH Pw and vtc
//      (MFMA k-sum is permutation-invariant) -> one dword Pw store per reg.
// LDS: Ks 24K + Vs 30K + Pw 11.25K = 65.25K -> still 2 blocks/CU.
// __launch_bounds__(576,5) caps VGPR at ~102 to keep 18 waves/CU resident.
// ---------------------------------------------------------------------------
#define RT_ 144   // rows per tile (9 waves x 16)

__global__ __launch_bounds__(576, 5) void attn_fused(
        const unsigned short* __restrict__ qg,
        const unsigned short* __restrict__ kg,
        const unsigned short* __restrict__ vtc,
        const unsigned short* __restrict__ bigtab,
        unsigned short* __restrict__ ob) {
    // Ks chunk ch = ct*128 + oct*16 + k16 holds K[key=t*96+ct*16+k16][oct*8..+8]
    // Vs: 3 ks-blocks of [64 dims][40 slots] (32 keys sigma-permuted + 8 pad)
    __shared__ __align__(16) unsigned short Ks[2][6144];   // 24 KB
    __shared__ __align__(16) unsigned short Vs[2][7680];   // 30 KB
    __shared__ __align__(16) unsigned short Pw[9][640];    // 11.25 KB

    int tid = threadIdx.x;
    int w = tid >> 6, lane = tid & 63;
    int quad = lane >> 4, l16 = lane & 15;

    int lin = blockIdx.x;
    int xcd = lin & 7;
    int u = lin >> 3;
    int bhi = u & 7;
    int mt = u >> 3;                 // 0..7
    int bh = xcd * 8 + bhi;
    int b = bh >> 3, h = bh & 7;

    const unsigned short* qp = qg + (size_t)bh * N_ * HD_;
    const unsigned short* kp = kg + (size_t)bh * N_ * HD_;
    const unsigned short* vp = vtc + (size_t)bh * VST * VCS;

    int rbase = mt * RT_ + w * 16 + quad * 4;   // C-layout row of reg 0
    const unsigned short* bt = bigtab + ((size_t)h * 1152 + rbase) * 1056 + l16;

    // Q fragments: wave owns rows mt*144 + w*16 + l16 (A-layout, clamped)
    short8 qf[2];
    {
        int row = min(mt * RT_ + w * 16 + l16, N_ - 1);
        qf[0] = *(const short8*)(qp + (size_t)row * HD_ + quad * 8);
        qf[1] = *(const short8*)(qp + (size_t)row * HD_ + 32 + quad * 8);
    }

    f32x4 o_acc[4], l_acc;
    const f32x4 zero4 = {0.f, 0.f, 0.f, 0.f};
#pragma unroll
    for (int g2 = 0; g2 < 4; g2++) o_acc[g2] = zero4;
    l_acc = zero4;
    short8 ones;
    {
        short one_bf = (short)0x3F80;
#pragma unroll
        for (int j = 0; j < 8; j++) ones[j] = one_bf;
    }

    // staging: waves 0-5 -> K (768 chunks, 2 rounds of 6 waves);
    //          waves 6-8 -> V (960 chunks, 5 rounds of 3 waves). Lane-linear.
    auto stage = [&](int t, int buf) {
        if (w < 6) {
#pragma unroll
            for (int r2 = 0; r2 < 2; r2++) {
                int cb = (r2 * 6 + w) * 64;      // base chunk
                int ch = cb + lane;
                int ct = ch >> 7, rem = ch & 127;
                int oct = rem >> 4, k16 = rem & 15;
                int key = min(t * 96 + ct * 16 + k16, N_ - 1);
                load_lds16(kp + (size_t)key * HD_ + oct * 8, &Ks[buf][cb * 8]);
            }
        } else {
            int wv = w - 6;
#pragma unroll
            for (int r2 = 0; r2 < 5; r2++) {
                int cb = (r2 * 3 + wv) * 64;
                load_lds16(vp + (size_t)t * 3 * VCS + (size_t)(cb + lane) * 8,
                           &Vs[buf][cb * 8]);
            }
        }
    };

    stage(0, 0);

#pragma unroll 1
    for (int t = 0; t < 11; t++) {
        int buf = t & 1;
        __syncthreads();                  // Ks/Vs[buf] ready (vmcnt drained)

        // bias prefetch FIRST (so waiting on it doesn't drain stage loads)
        unsigned short blv[3][2][4];
        const unsigned short* btp = bt + t * 96;
#pragma unroll
        for (int ks = 0; ks < 3; ks++)
#pragma unroll
            for (int ctl = 0; ctl < 2; ctl++)
#pragma unroll
                for (int reg = 0; reg < 4; reg++)
                    blv[ks][ctl][reg] = btp[reg * 1056 + (ks * 2 + ctl) * 16];

        if (t < 10) stage(t + 1, buf ^ 1);

        // ---- QK: S[16 rows][96 cols] = 6 ct tiles ----
        f32x4 s[6];
#pragma unroll
        for (int ct = 0; ct < 6; ct++) {
            short8 kf0 = *(const short8*)&Ks[buf][(ct * 128 + quad * 16 + l16) * 8];
            short8 kf1 = *(const short8*)&Ks[buf][(ct * 128 + (4 + quad) * 16 + l16) * 8];
            s[ct] = __builtin_amdgcn_mfma_f32_16x16x32_bf16(qf[0], kf0, zero4, 0, 0, 0);
            s[ct] = __builtin_amdgcn_mfma_f32_16x16x32_bf16(qf[1], kf1, s[ct], 0, 0, 0);
        }

        // ---- 3 steps of 32 cols: exp2+pack (dword Pw stores), then PV ----
#pragma unroll
        for (int ks = 0; ks < 3; ks++) {
#pragma unroll
            for (int reg = 0; reg < 4; reg++) {
                float bia0 = __half2float(*(const __half*)&blv[ks][0][reg]);
                float bia1 = __half2float(*(const __half*)&blv[ks][1][reg]);
                float p0 = fexp2(s[ks * 2][reg] + bia0);
                float p1 = fexp2(s[ks * 2 + 1][reg] + bia1);
                ushort2 pp;
                pp.x = bf16u(p0);
                pp.y = bf16u(p1);
                // key = ctl*16+l16 stored at sigma(key) = l16*2+ctl
                *(ushort2*)&Pw[w][(quad * 4 + reg) * 40 + l16 * 2] = pp;
            }
            // PV for this 32-key step; V slots sigma-permuted to match Pw
            short8 pf = *(const short8*)&Pw[w][l16 * 40 + quad * 8];
            const unsigned short* vcp = &Vs[buf][ks * 2560 + quad * 8];
#pragma unroll
            for (int g2 = 0; g2 < 4; g2++) {
                short8 vf = *(const short8*)(vcp + (g2 * 16 + l16) * 40);
                o_acc[g2] = __builtin_amdgcn_mfma_f32_16x16x32_bf16(
                    pf, vf, o_acc[g2], 0, 0, 0);
            }
            l_acc = __builtin_amdgcn_mfma_f32_16x16x32_bf16(pf, ones, l_acc, 0, 0, 0);
        }
    }

    // ---- epilogue: o/l -> ob bf16 (C-layout rows; pad rows skip store) ----
#pragma unroll
    for (int reg = 0; reg < 4; reg++) {
        int r = rbase + reg;
        if (r < N_) {
            float inv = 1.0f / l_acc[reg];
            unsigned short* orow = ob + ((size_t)b * N_ + r) * C_ + h * HD_ + l16;
#pragma unroll
            for (int g2 = 0; g2 < 4; g2++)
                orow[g2 * 16] = bf16u(o_acc[g2][reg] * inv);
        }
    }
}

// ---------------------------------------------------------------------------
extern "C" void kernel_launch(void* const* d_in, const int* in_sizes, int n_in,
                              void* d_out, int out_size, void* d_ws, size_t ws_size,
                              hipStream_t stream) {
    const float* x      = (const float*)d_in[0];
    const float* qkv_w  = (const float*)d_in[1];
    const float* proj_w = (const float*)d_in[2];
    const float* proj_b = (const float*)d_in[3];
    const float* wg_w   = (const float*)d_in[4];
    const float* wg_b   = (const float*)d_in[5];
    float* out = (float*)d_out;

    const size_t per = PER_;
    char* ws = (char*)d_ws;
    float* tab             = (float*)ws;                            //     32,768 B
    unsigned short* bigtab = (unsigned short*)(ws + (32 << 10));    // 19,464,192 B
    unsigned short* xb     = bigtab + (size_t)8 * 1152 * 1056;      //  8,396,800 B
    unsigned short* wqkvb  = xb + per;                              //  1,572,864 B
    unsigned short* wprjb  = wqkvb + (size_t)SZ_QKVW;               //    524,288 B
    unsigned short* qb     = wprjb + (size_t)SZ_PRJW;               //  8,396,800 B
    unsigned short* kb     = qb + per;                              //  8,396,800 B
    unsigned short* vtc    = kb + per;                              // 11,796,480 B
    unsigned short* ob     = vtc + (size_t)64 * VST * VCS;          //  8,396,800 B

    prep_kernel<<<32 + CAST_BLKS, 256, 0, stream>>>(x, qkv_w, proj_w, wg_w, wg_b,
                                                    xb, wqkvb, wprjb, tab);
    bias_expand<<<4752, 256, 0, stream>>>(tab, bigtab);
    gemm_qkv_mfma<<<dim3(12, 65), 256, 0, stream>>>(xb, wqkvb, qb, kb, vtc);
    attn_fused<<<8 * 8 * 8, 576, 0, stream>>>(qb, kb, vtc, bigtab, ob);
    gemm_proj_mfma<<<dim3(4, 65), 256, 0, stream>>>(ob, wprjb, proj_b, out);
}

// Round 2
// 192.167 us; speedup vs baseline: 1.1958x; 1.1958x over previous
//
#include <hip/hip_runtime.h>
#include <hip/hip_bf16.h>
#include <hip/hip_fp16.h>
#include <math.h>

#define B_  8
#define N_  1025
#define C_  512
#define H_  8
#define HD_ 64
#define M_  (B_ * N_)   // 8200
#define VCS 2560        // shorts per vtc chunk-block: 64 dims * 40 (32 keys + 8 pad)
#define VST 36          // vtc chunk-blocks per bh (33 used)

typedef __attribute__((ext_vector_type(8))) short short8;
typedef __attribute__((ext_vector_type(4))) float f32x4;
typedef __attribute__((ext_vector_type(4))) unsigned short us4;

__device__ inline unsigned short bf16u(float x) {
    __hip_bfloat16 t = __float2bfloat16(x);
    return *(unsigned short*)&t;
}
__device__ inline float fexp2(float x) {   // 2^x via v_exp_f32
    float r;
    asm("v_exp_f32 %0, %1" : "=v"(r) : "v"(x));
    return r;
}
__device__ inline float h2f(unsigned short u) {
    __half_raw hr; hr.x = u;
    return __half2float(__half(hr));
}
__device__ inline void load_lds16(const void* g, void* l) {
    __builtin_amdgcn_global_load_lds(
        (const __attribute__((address_space(1))) unsigned int*)g,
        (__attribute__((address_space(3))) unsigned int*)l, 16, 0, 0);
}

// ---------------------------------------------------------------------------
// Fused prep:
//   blocks [0,256): bigtab expansion. Block owns (h, 36-row stripe): recompute
//     the 1024-entry head table in LDS (4 MLP evals/thread), then expand to
//     bigtab[h][r][c] fp16 log2-scaled with pad row/col-0 = 0 and c>1024 =
//     -60000 baked in. Folding this here removes the extra dispatch R1 added.
//   blocks [256, ...): f32 -> bf16 casts of x / qkv_w / proj_w.
// ---------------------------------------------------------------------------
#define PER_ ((size_t)B_ * H_ * N_ * HD_)      // 4,198,400
#define SZ_QKVW (3 * C_ * C_)
#define SZ_PRJW (C_ * C_)
#define CAST_BLKS ((4198400 + 786432 + 262144) / 4 / 256)   // 5124
#define EXP_BLKS 256

__global__ void prep_kernel(const float* __restrict__ x,
                            const float* __restrict__ qkv_w,
                            const float* __restrict__ proj_w,
                            const float* __restrict__ wg_w,
                            const float* __restrict__ wg_b,
                            unsigned short* __restrict__ xb,
                            unsigned short* __restrict__ wqkvb,
                            unsigned short* __restrict__ wprjb,
                            unsigned short* __restrict__ big) {
    __shared__ float tl[1024];
    int blk = blockIdx.x;
    int tid = threadIdx.x;
    if (blk < EXP_BLKS) {
        int h = blk >> 5, rs = blk & 31;
        const float* w = wg_w + h * 64;
        float wb = wg_b[h];
#pragma unroll 1
        for (int e = tid; e < 1024; e += 256) {
            int a = e >> 5, b = e & 31;
            float dx = logf(fmaxf((float)a * (1.0f / 33.0f), 0.001f));
            float dy = logf(fmaxf((float)b * (1.0f / 33.0f), 0.001f));
            float acc = wb;
#pragma unroll
            for (int k = 0; k < 8; k++) {
                float f = powf(1000.0f, -(float)k * 0.125f);
                float X = 100.0f * dx * f;
                float Y = 100.0f * dy * f;
                acc += w[k]      * sinf(X);
                acc += w[8 + k]  * sinf(Y);
                acc += w[32 + k] * cosf(X);
                acc += w[40 + k] * cosf(Y);
                acc += w[48 + k] + w[56 + k];
            }
            tl[e] = log2f(fmaxf(fmaxf(acc, 0.0f), 1e-6f));
        }
        __syncthreads();
        int rbase = rs * 36;
#pragma unroll 1
        for (int e8 = tid; e8 < 36 * 132; e8 += 256) {
            int rr = e8 / 132;
            int cg = e8 - rr * 132;
            int r = rbase + rr;
            int c0 = cg * 8;
            int i = min(r, 1024) - 1;
            int ix = i >> 5, iy = i & 31;
            unsigned short o8[8];
#pragma unroll
            for (int e = 0; e < 8; e++) {
                int c = c0 + e;
                float v;
                if (r == 0 || c == 0) v = 0.f;
                else if (c > 1024)    v = -60000.f;
                else {
                    int j = c - 1;
                    int da = __sad(ix, j >> 5, 0u);
                    int db = __sad(iy, j & 31, 0u);
                    v = tl[da * 32 + db];
                }
                __half hv = __float2half(v);
                o8[e] = *(unsigned short*)&hv;
            }
            *(short8*)(big + ((size_t)h * 1152 + r) * 1056 + c0) = *(short8*)o8;
        }
        return;
    }
    long i4 = ((long)(blk - EXP_BLKS) * 256 + tid) * 4;
    const float* src;
    unsigned short* dst;
    long off;
    if (i4 < (long)PER_)                    { src = x;      dst = xb;    off = i4; }
    else if (i4 < (long)PER_ + SZ_QKVW)     { src = qkv_w;  dst = wqkvb; off = i4 - PER_; }
    else                                    { src = proj_w; dst = wprjb; off = i4 - PER_ - SZ_QKVW; }
    float4 v = *(const float4*)(src + off);
    ushort4 p;
    p.x = bf16u(v.x); p.y = bf16u(v.y); p.z = bf16u(v.z); p.w = bf16u(v.w);
    *(ushort4*)(dst + off) = p;
}

// ---------------------------------------------------------------------------
// MFMA GEMM, 128x128 tile, BK=32, 4 waves. q scaled by 0.125*log2(e).
// v scattered to vtc with key-slot permutation
//   sigma(k) = ((k>>2)&3)*8 + ((k>>4)<<2) + (k&3)
// matching the in-register P fragment of the swapped-QK attention, and
// 40-stride dim rows (8-slot pad) for LDS bank spread.
// ---------------------------------------------------------------------------
#define GK 512

__global__ __launch_bounds__(256) void gemm_qkv_mfma(
        const unsigned short* __restrict__ A, const unsigned short* __restrict__ W,
        unsigned short* __restrict__ qb, unsigned short* __restrict__ kb,
        unsigned short* __restrict__ vtc) {
    __shared__ __align__(16) unsigned short As[128 * 32];
    __shared__ __align__(16) unsigned short Bs[128 * 32];
    int tid = threadIdx.x;
    int w = tid >> 6, lane = tid & 63;
    int quad = lane >> 4, l16 = lane & 15;
    int m0 = blockIdx.y * 128;
    int n0 = blockIdx.x * 128;
    int wr = (w >> 1) * 64, wc = (w & 1) * 64;

    int c0 = tid, c1 = tid + 256;
    int a_r0 = min(m0 + (c0 >> 2), M_ - 1), a_c0 = (c0 & 3) * 8;
    int a_r1 = min(m0 + (c1 >> 2), M_ - 1), a_c1 = (c1 & 3) * 8;
    int b_r0 = n0 + (c0 >> 2), b_r1 = n0 + (c1 >> 2);

    int which = n0 >> 9;                       // 0=q 1=k 2=v
    int h = ((n0 + wc) >> 6) & 7;

    f32x4 acc[4][4];
    const f32x4 zero4 = {0.f, 0.f, 0.f, 0.f};
#pragma unroll
    for (int mi = 0; mi < 4; mi++)
#pragma unroll
        for (int ni = 0; ni < 4; ni++) acc[mi][ni] = zero4;

    for (int k0 = 0; k0 < GK; k0 += 32) {
        __syncthreads();
        load_lds16(A + (size_t)a_r0 * GK + k0 + a_c0, &As[w * 512]);
        load_lds16(A + (size_t)a_r1 * GK + k0 + a_c1, &As[2048 + w * 512]);
        load_lds16(W + (size_t)b_r0 * GK + k0 + a_c0, &Bs[w * 512]);
        load_lds16(W + (size_t)b_r1 * GK + k0 + a_c1, &Bs[2048 + w * 512]);
        __syncthreads();
        short8 af[4], bf[4];
#pragma unroll
        for (int mi = 0; mi < 4; mi++)
            af[mi] = *(const short8*)&As[(wr + mi * 16 + l16) * 32 + quad * 8];
#pragma unroll
        for (int ni = 0; ni < 4; ni++)
            bf[ni] = *(const short8*)&Bs[(wc + ni * 16 + l16) * 32 + quad * 8];
#pragma unroll
        for (int mi = 0; mi < 4; mi++)
#pragma unroll
            for (int ni = 0; ni < 4; ni++)
                acc[mi][ni] = __builtin_amdgcn_mfma_f32_16x16x32_bf16(
                    bf[ni], af[mi], acc[mi][ni], 0, 0, 0);
    }

    if (which < 2) {
        unsigned short* dst = (which == 0) ? qb : kb;
        float sc = (which == 0) ? 0.18033688f : 1.0f;   // 0.125 * log2(e)
#pragma unroll
        for (int mi = 0; mi < 4; mi++) {
            int m = m0 + wr + mi * 16 + l16;
            if (m < M_) {
                int bb = m / N_;
                int i  = m - bb * N_;
                unsigned short* row = dst + ((size_t)(bb * H_ + h) * N_ + i) * HD_;
#pragma unroll
                for (int ni = 0; ni < 4; ni++) {
                    ushort4 pk;
                    pk.x = bf16u(acc[mi][ni][0] * sc);
                    pk.y = bf16u(acc[mi][ni][1] * sc);
                    pk.z = bf16u(acc[mi][ni][2] * sc);
                    pk.w = bf16u(acc[mi][ni][3] * sc);
                    *(ushort4*)(row + ni * 16 + quad * 4) = pk;
                }
            }
        }
    } else {
#pragma unroll
        for (int mi = 0; mi < 4; mi++) {
            int m = m0 + wr + mi * 16 + l16;
            if (m < M_) {
                int bb = m / N_;
                int i  = m - bb * N_;
                int ch = i >> 5, key = i & 31;
                int slot = ((key >> 2) & 3) * 8 + ((key >> 4) << 2) + (key & 3);
                unsigned short* base = vtc + ((size_t)(bb * H_ + h) * VST + ch) * VCS + slot;
#pragma unroll
                for (int ni = 0; ni < 4; ni++)
#pragma unroll
                    for (int reg = 0; reg < 4; reg++)
                        base[(ni * 16 + quad * 4 + reg) * 40] = bf16u(acc[mi][ni][reg]);
            }
        }
    }
}

__global__ __launch_bounds__(256) void gemm_proj_mfma(
        const unsigned short* __restrict__ A, const unsigned short* __restrict__ W,
        const float* __restrict__ bias, float* __restrict__ out) {
    __shared__ __align__(16) unsigned short As[128 * 32];
    __shared__ __align__(16) unsigned short Bs[128 * 32];
    int tid = threadIdx.x;
    int w = tid >> 6, lane = tid & 63;
    int quad = lane >> 4, l16 = lane & 15;
    int m0 = blockIdx.y * 128;
    int n0 = blockIdx.x * 128;
    int wr = (w >> 1) * 64, wc = (w & 1) * 64;

    int c0 = tid, c1 = tid + 256;
    int a_r0 = min(m0 + (c0 >> 2), M_ - 1), a_c0 = (c0 & 3) * 8;
    int a_r1 = min(m0 + (c1 >> 2), M_ - 1), a_c1 = (c1 & 3) * 8;
    int b_r0 = n0 + (c0 >> 2), b_r1 = n0 + (c1 >> 2);

    f32x4 acc[4][4];
    const f32x4 zero4 = {0.f, 0.f, 0.f, 0.f};
#pragma unroll
    for (int mi = 0; mi < 4; mi++)
#pragma unroll
        for (int ni = 0; ni < 4; ni++) acc[mi][ni] = zero4;

    for (int k0 = 0; k0 < GK; k0 += 32) {
        __syncthreads();
        load_lds16(A + (size_t)a_r0 * GK + k0 + a_c0, &As[w * 512]);
        load_lds16(A + (size_t)a_r1 * GK + k0 + a_c1, &As[2048 + w * 512]);
        load_lds16(W + (size_t)b_r0 * GK + k0 + a_c0, &Bs[w * 512]);
        load_lds16(W + (size_t)b_r1 * GK + k0 + a_c1, &Bs[2048 + w * 512]);
        __syncthreads();
        short8 af[4], bf[4];
#pragma unroll
        for (int mi = 0; mi < 4; mi++)
            af[mi] = *(const short8*)&As[(wr + mi * 16 + l16) * 32 + quad * 8];
#pragma unroll
        for (int ni = 0; ni < 4; ni++)
            bf[ni] = *(const short8*)&Bs[(wc + ni * 16 + l16) * 32 + quad * 8];
#pragma unroll
        for (int mi = 0; mi < 4; mi++)
#pragma unroll
            for (int ni = 0; ni < 4; ni++)
                acc[mi][ni] = __builtin_amdgcn_mfma_f32_16x16x32_bf16(
                    af[mi], bf[ni], acc[mi][ni], 0, 0, 0);
    }

    float bvals[4];
#pragma unroll
    for (int ni = 0; ni < 4; ni++) bvals[ni] = bias[n0 + wc + ni * 16 + l16];
#pragma unroll
    for (int mi = 0; mi < 4; mi++)
#pragma unroll
        for (int reg = 0; reg < 4; reg++) {
            int m = m0 + wr + mi * 16 + quad * 4 + reg;
            if (m < M_) {
                float* row = out + (size_t)m * C_ + n0 + wc;
#pragma unroll
                for (int ni = 0; ni < 4; ni++)
                    row[ni * 16 + l16] = acc[mi][ni][reg] + bvals[ni];
            }
        }
}

// ---------------------------------------------------------------------------
// FUSED attention v7: swapped-operand QK (s = mfma(K, Q)) puts S's query on
// the D-column (l16) so each lane holds P for exactly its own PV A-fragment
// slots -> the ENTIRE Pw LDS round-trip (12 ds_writes + 3 b128 reads + 3 LDS
// turnarounds per wave-tile on the critical path) is deleted; P goes
// registers-only. V's key->slot map sigma matches in gemm. Bias is register-
// prefetched ONE TILE AHEAD (R1 showed in-tile bigtab loads put L2/L3 latency
// on the critical path). Staging balanced: every wave issues exactly 3
// global_load_lds. setprio(1) around MFMA clusters (T5, attn-positive m191).
// LDS: Ks 24K + Vs 30K = 54K -> 2 blocks/CU.
// ---------------------------------------------------------------------------
#define RT_ 144   // rows per tile (9 waves x 16)

__global__ __launch_bounds__(576, 4) void attn_fused(
        const unsigned short* __restrict__ qg,
        const unsigned short* __restrict__ kg,
        const unsigned short* __restrict__ vtc,
        const unsigned short* __restrict__ bigtab,
        unsigned short* __restrict__ ob) {
    // Ks chunk ch = ct*128 + oct*16 + k16 holds K[key=t*96+ct*16+k16][oct*8..+8]
    // Vs: 3 ks-blocks of [64 dims][40 slots] (32 keys sigma-permuted + 8 pad)
    __shared__ __align__(16) unsigned short Ks[2][6144];   // 24 KB
    __shared__ __align__(16) unsigned short Vs[2][7680];   // 30 KB

    int tid = threadIdx.x;
    int w = tid >> 6, lane = tid & 63;
    int quad = lane >> 4, l16 = lane & 15;

    int lin = blockIdx.x;
    int xcd = lin & 7;
    int u = lin >> 3;
    int bhi = u & 7;
    int mt = u >> 3;                 // 0..7
    int bh = xcd * 8 + bhi;
    int b = bh >> 3, h = bh & 7;

    const unsigned short* qp = qg + (size_t)bh * N_ * HD_;
    const unsigned short* kp = kg + (size_t)bh * N_ * HD_;
    const unsigned short* vp = vtc + (size_t)bh * VST * VCS;

    int qrow = mt * RT_ + w * 16 + l16;          // A-layout query row (0..1151)
    const unsigned short* bt = bigtab + ((size_t)h * 1152 + qrow) * 1056 + quad * 4;

    // Q fragments (A... now B-operand; same layout: lane l16 = query row)
    short8 qf[2];
    {
        int row = min(qrow, N_ - 1);
        qf[0] = *(const short8*)(qp + (size_t)row * HD_ + quad * 8);
        qf[1] = *(const short8*)(qp + (size_t)row * HD_ + 32 + quad * 8);
    }

    f32x4 o_acc[4], l_acc;
    const f32x4 zero4 = {0.f, 0.f, 0.f, 0.f};
#pragma unroll
    for (int g2 = 0; g2 < 4; g2++) o_acc[g2] = zero4;
    l_acc = zero4;
    short8 ones;
    {
        short one_bf = (short)0x3F80;
#pragma unroll
        for (int j = 0; j < 8; j++) ones[j] = one_bf;
    }

    // balanced staging: 27 64-chunk blocks (12 K + 15 V), 3 per wave.
    auto stage = [&](int t, int buf) {
#pragma unroll
        for (int r2 = 0; r2 < 3; r2++) {
            int cb = w * 3 + r2;                 // 0..26, uniform per wave
            if (cb < 12) {
                int ch = cb * 64 + lane;
                int ct = ch >> 7, rem = ch & 127;
                int oct = rem >> 4, k16 = rem & 15;
                int key = min(t * 96 + ct * 16 + k16, N_ - 1);
                load_lds16(kp + (size_t)key * HD_ + oct * 8, &Ks[buf][cb * 512]);
            } else {
                int vb = cb - 12;
                load_lds16(vp + (size_t)t * 3 * VCS + (size_t)(vb * 64 + lane) * 8,
                           &Vs[buf][vb * 512]);
            }
        }
    };

    // bias register prefetch: 6 ushort4 per tile (ks*2+parity, 4 regs each)
    us4 bcur[6], bnx[6];
#pragma unroll
    for (int i = 0; i < 6; i++)
        bnx[i] = *(const us4*)(bt + (i >> 1) * 32 + (i & 1) * 16);
    stage(0, 0);

#pragma unroll 1
    for (int t = 0; t < 11; t++) {
        int buf = t & 1;
        __syncthreads();                  // Ks/Vs[buf] ready (vmcnt drained)

#pragma unroll
        for (int i = 0; i < 6; i++) bcur[i] = bnx[i];
        if (t < 10) {
            const unsigned short* btp = bt + (t + 1) * 96;
#pragma unroll
            for (int i = 0; i < 6; i++)
                bnx[i] = *(const us4*)(btp + (i >> 1) * 32 + (i & 1) * 16);
            stage(t + 1, buf ^ 1);
        }

        // ---- QK swapped: s[ct] rows=keys (quad*4+reg), cols=query (l16) ----
        f32x4 s[6];
        __builtin_amdgcn_s_setprio(1);
#pragma unroll
        for (int ct = 0; ct < 6; ct++) {
            short8 kf0 = *(const short8*)&Ks[buf][(ct * 128 + quad * 16 + l16) * 8];
            short8 kf1 = *(const short8*)&Ks[buf][(ct * 128 + (4 + quad) * 16 + l16) * 8];
            s[ct] = __builtin_amdgcn_mfma_f32_16x16x32_bf16(kf0, qf[0], zero4, 0, 0, 0);
            s[ct] = __builtin_amdgcn_mfma_f32_16x16x32_bf16(kf1, qf[1], s[ct], 0, 0, 0);
        }
        __builtin_amdgcn_s_setprio(0);

        // ---- 3 steps of 32 keys: registers-only softmax, then PV ----
        // P slot quad*8+e <- key = (e>>2)*16 + quad*4 + (e&3)  (= sigma)
#pragma unroll
        for (int ks = 0; ks < 3; ks++) {
            short8 pf;
#pragma unroll
            for (int e = 0; e < 8; e++) {
                int par = e >> 2, r = e & 3;
                float bia = h2f(bcur[ks * 2 + par][r]);
                float p = fexp2(s[ks * 2 + par][r] + bia);
                pf[e] = (short)bf16u(p);
            }
            const unsigned short* vcp = &Vs[buf][ks * 2560 + quad * 8];
            __builtin_amdgcn_s_setprio(1);
#pragma unroll
            for (int g2 = 0; g2 < 4; g2++) {
                short8 vf = *(const short8*)(vcp + (g2 * 16 + l16) * 40);
                o_acc[g2] = __builtin_amdgcn_mfma_f32_16x16x32_bf16(
                    pf, vf, o_acc[g2], 0, 0, 0);
            }
            l_acc = __builtin_amdgcn_mfma_f32_16x16x32_bf16(pf, ones, l_acc, 0, 0, 0);
            __builtin_amdgcn_s_setprio(0);
        }
    }

    // ---- epilogue: o/l -> ob bf16 (C-layout rows = query; pad rows skip) ----
    int rbase = mt * RT_ + w * 16 + quad * 4;
#pragma unroll
    for (int reg = 0; reg < 4; reg++) {
        int r = rbase + reg;
        if (r < N_) {
            float inv = 1.0f / l_acc[reg];
            unsigned short* orow = ob + ((size_t)b * N_ + r) * C_ + h * HD_ + l16;
#pragma unroll
            for (int g2 = 0; g2 < 4; g2++)
                orow[g2 * 16] = bf16u(o_acc[g2][reg] * inv);
        }
    }
}

// ---------------------------------------------------------------------------
extern "C" void kernel_launch(void* const* d_in, const int* in_sizes, int n_in,
                              void* d_out, int out_size, void* d_ws, size_t ws_size,
                              hipStream_t stream) {
    const float* x      = (const float*)d_in[0];
    const float* qkv_w  = (const float*)d_in[1];
    const float* proj_w = (const float*)d_in[2];
    const float* proj_b = (const float*)d_in[3];
    const float* wg_w   = (const float*)d_in[4];
    const float* wg_b   = (const float*)d_in[5];
    float* out = (float*)d_out;

    const size_t per = PER_;
    char* ws = (char*)d_ws;
    unsigned short* bigtab = (unsigned short*)ws;                   // 19,464,192 B
    unsigned short* xb     = bigtab + (size_t)8 * 1152 * 1056;      //  8,396,800 B
    unsigned short* wqkvb  = xb + per;                              //  1,572,864 B
    unsigned short* wprjb  = wqkvb + (size_t)SZ_QKVW;               //    524,288 B
    unsigned short* qb     = wprjb + (size_t)SZ_PRJW;               //  8,396,800 B
    unsigned short* kb     = qb + per;                              //  8,396,800 B
    unsigned short* vtc    = kb + per;                              // 11,796,480 B
    unsigned short* ob     = vtc + (size_t)64 * VST * VCS;          //  8,396,800 B

    prep_kernel<<<EXP_BLKS + CAST_BLKS, 256, 0, stream>>>(x, qkv_w, proj_w, wg_w, wg_b,
                                                          xb, wqkvb, wprjb, bigtab);
    gemm_qkv_mfma<<<dim3(12, 65), 256, 0, stream>>>(xb, wqkvb, qb, kb, vtc);
    attn_fused<<<8 * 8 * 8, 576, 0, stream>>>(qb, kb, vtc, bigtab, ob);
    gemm_proj_mfma<<<dim3(4, 65), 256, 0, stream>>>(ob, wprjb, proj_b, out);
}

// Round 3
// 185.157 us; speedup vs baseline: 1.2411x; 1.0379x over previous
//
#include <hip/hip_runtime.h>
#include <hip/hip_bf16.h>
#include <hip/hip_fp16.h>
#include <math.h>

#define B_  8
#define N_  1025
#define C_  512
#define H_  8
#define HD_ 64
#define M_  (B_ * N_)   // 8200
#define VCS 2560        // shorts per vtc chunk-block: 64 dims * 40 (32 keys + 8 pad)
#define VST 36          // vtc chunk-blocks per bh (33 used)

typedef __attribute__((ext_vector_type(8))) short short8;
typedef __attribute__((ext_vector_type(4))) float f32x4;
typedef __attribute__((ext_vector_type(4))) unsigned short us4;

__device__ inline unsigned short bf16u(float x) {
    __hip_bfloat16 t = __float2bfloat16(x);
    return *(unsigned short*)&t;
}
__device__ inline float fexp2(float x) {   // 2^x via v_exp_f32
    float r;
    asm("v_exp_f32 %0, %1" : "=v"(r) : "v"(x));
    return r;
}
__device__ inline float h2f(unsigned short u) {
    __half_raw hr; hr.x = u;
    return __half2float(__half(hr));
}
__device__ inline void load_lds16(const void* g, void* l) {
    __builtin_amdgcn_global_load_lds(
        (const __attribute__((address_space(1))) unsigned int*)g,
        (__attribute__((address_space(3))) unsigned int*)l, 16, 0, 0);
}

// ---------------------------------------------------------------------------
// Fused prep:
//   blocks [0,256): bigtab expansion (per-h table recomputed in LDS, expanded
//     to bigtab[h][r][c] fp16 log2-scaled; pad row/col-0 = 0, c>1024 = -60000).
//   blocks [256, ...): f32 -> bf16 casts of x / qkv_w / proj_w.
// ---------------------------------------------------------------------------
#define PER_ ((size_t)B_ * H_ * N_ * HD_)      // 4,198,400
#define SZ_QKVW (3 * C_ * C_)
#define SZ_PRJW (C_ * C_)
#define CAST_BLKS ((4198400 + 786432 + 262144) / 4 / 256)   // 5124
#define EXP_BLKS 256

__global__ void prep_kernel(const float* __restrict__ x,
                            const float* __restrict__ qkv_w,
                            const float* __restrict__ proj_w,
                            const float* __restrict__ wg_w,
                            const float* __restrict__ wg_b,
                            unsigned short* __restrict__ xb,
                            unsigned short* __restrict__ wqkvb,
                            unsigned short* __restrict__ wprjb,
                            unsigned short* __restrict__ big) {
    __shared__ float tl[1024];
    int blk = blockIdx.x;
    int tid = threadIdx.x;
    if (blk < EXP_BLKS) {
        int h = blk >> 5, rs = blk & 31;
        const float* w = wg_w + h * 64;
        float wb = wg_b[h];
#pragma unroll 1
        for (int e = tid; e < 1024; e += 256) {
            int a = e >> 5, b = e & 31;
            float dx = logf(fmaxf((float)a * (1.0f / 33.0f), 0.001f));
            float dy = logf(fmaxf((float)b * (1.0f / 33.0f), 0.001f));
            float acc = wb;
#pragma unroll
            for (int k = 0; k < 8; k++) {
                float f = powf(1000.0f, -(float)k * 0.125f);
                float X = 100.0f * dx * f;
                float Y = 100.0f * dy * f;
                acc += w[k]      * sinf(X);
                acc += w[8 + k]  * sinf(Y);
                acc += w[32 + k] * cosf(X);
                acc += w[40 + k] * cosf(Y);
                acc += w[48 + k] + w[56 + k];
            }
            tl[e] = log2f(fmaxf(fmaxf(acc, 0.0f), 1e-6f));
        }
        __syncthreads();
        int rbase = rs * 36;
#pragma unroll 1
        for (int e8 = tid; e8 < 36 * 132; e8 += 256) {
            int rr = e8 / 132;
            int cg = e8 - rr * 132;
            int r = rbase + rr;
            int c0 = cg * 8;
            int i = min(r, 1024) - 1;
            int ix = i >> 5, iy = i & 31;
            unsigned short o8[8];
#pragma unroll
            for (int e = 0; e < 8; e++) {
                int c = c0 + e;
                float v;
                if (r == 0 || c == 0) v = 0.f;
                else if (c > 1024)    v = -60000.f;
                else {
                    int j = c - 1;
                    int da = __sad(ix, j >> 5, 0u);
                    int db = __sad(iy, j & 31, 0u);
                    v = tl[da * 32 + db];
                }
                __half hv = __float2half(v);
                o8[e] = *(unsigned short*)&hv;
            }
            *(short8*)(big + ((size_t)h * 1152 + r) * 1056 + c0) = *(short8*)o8;
        }
        return;
    }
    long i4 = ((long)(blk - EXP_BLKS) * 256 + tid) * 4;
    const float* src;
    unsigned short* dst;
    long off;
    if (i4 < (long)PER_)                    { src = x;      dst = xb;    off = i4; }
    else if (i4 < (long)PER_ + SZ_QKVW)     { src = qkv_w;  dst = wqkvb; off = i4 - PER_; }
    else                                    { src = proj_w; dst = wprjb; off = i4 - PER_ - SZ_QKVW; }
    float4 v = *(const float4*)(src + off);
    ushort4 p;
    p.x = bf16u(v.x); p.y = bf16u(v.y); p.z = bf16u(v.z); p.w = bf16u(v.w);
    *(ushort4*)(dst + off) = p;
}

// ---------------------------------------------------------------------------
// MFMA GEMM, 128x128 tile, BK=32, 4 waves. q scaled by 0.125*log2(e).
// v scattered to vtc with key-slot permutation
//   sigma(k) = ((k>>2)&3)*8 + ((k>>4)<<2) + (k&3)
// matching the in-register P fragment of the swapped-QK attention, and
// 40-stride dim rows (8-slot pad) for LDS bank spread.
// ---------------------------------------------------------------------------
#define GK 512

__global__ __launch_bounds__(256) void gemm_qkv_mfma(
        const unsigned short* __restrict__ A, const unsigned short* __restrict__ W,
        unsigned short* __restrict__ qb, unsigned short* __restrict__ kb,
        unsigned short* __restrict__ vtc) {
    __shared__ __align__(16) unsigned short As[128 * 32];
    __shared__ __align__(16) unsigned short Bs[128 * 32];
    int tid = threadIdx.x;
    int w = tid >> 6, lane = tid & 63;
    int quad = lane >> 4, l16 = lane & 15;
    int m0 = blockIdx.y * 128;
    int n0 = blockIdx.x * 128;
    int wr = (w >> 1) * 64, wc = (w & 1) * 64;

    int c0 = tid, c1 = tid + 256;
    int a_r0 = min(m0 + (c0 >> 2), M_ - 1), a_c0 = (c0 & 3) * 8;
    int a_r1 = min(m0 + (c1 >> 2), M_ - 1), a_c1 = (c1 & 3) * 8;
    int b_r0 = n0 + (c0 >> 2), b_r1 = n0 + (c1 >> 2);

    int which = n0 >> 9;                       // 0=q 1=k 2=v
    int h = ((n0 + wc) >> 6) & 7;

    f32x4 acc[4][4];
    const f32x4 zero4 = {0.f, 0.f, 0.f, 0.f};
#pragma unroll
    for (int mi = 0; mi < 4; mi++)
#pragma unroll
        for (int ni = 0; ni < 4; ni++) acc[mi][ni] = zero4;

    for (int k0 = 0; k0 < GK; k0 += 32) {
        __syncthreads();
        load_lds16(A + (size_t)a_r0 * GK + k0 + a_c0, &As[w * 512]);
        load_lds16(A + (size_t)a_r1 * GK + k0 + a_c1, &As[2048 + w * 512]);
        load_lds16(W + (size_t)b_r0 * GK + k0 + a_c0, &Bs[w * 512]);
        load_lds16(W + (size_t)b_r1 * GK + k0 + a_c1, &Bs[2048 + w * 512]);
        __syncthreads();
        short8 af[4], bf[4];
#pragma unroll
        for (int mi = 0; mi < 4; mi++)
            af[mi] = *(const short8*)&As[(wr + mi * 16 + l16) * 32 + quad * 8];
#pragma unroll
        for (int ni = 0; ni < 4; ni++)
            bf[ni] = *(const short8*)&Bs[(wc + ni * 16 + l16) * 32 + quad * 8];
#pragma unroll
        for (int mi = 0; mi < 4; mi++)
#pragma unroll
            for (int ni = 0; ni < 4; ni++)
                acc[mi][ni] = __builtin_amdgcn_mfma_f32_16x16x32_bf16(
                    bf[ni], af[mi], acc[mi][ni], 0, 0, 0);
    }

    if (which < 2) {
        unsigned short* dst = (which == 0) ? qb : kb;
        float sc = (which == 0) ? 0.18033688f : 1.0f;   // 0.125 * log2(e)
#pragma unroll
        for (int mi = 0; mi < 4; mi++) {
            int m = m0 + wr + mi * 16 + l16;
            if (m < M_) {
                int bb = m / N_;
                int i  = m - bb * N_;
                unsigned short* row = dst + ((size_t)(bb * H_ + h) * N_ + i) * HD_;
#pragma unroll
                for (int ni = 0; ni < 4; ni++) {
                    ushort4 pk;
                    pk.x = bf16u(acc[mi][ni][0] * sc);
                    pk.y = bf16u(acc[mi][ni][1] * sc);
                    pk.z = bf16u(acc[mi][ni][2] * sc);
                    pk.w = bf16u(acc[mi][ni][3] * sc);
                    *(ushort4*)(row + ni * 16 + quad * 4) = pk;
                }
            }
        }
    } else {
#pragma unroll
        for (int mi = 0; mi < 4; mi++) {
            int m = m0 + wr + mi * 16 + l16;
            if (m < M_) {
                int bb = m / N_;
                int i  = m - bb * N_;
                int ch = i >> 5, key = i & 31;
                int slot = ((key >> 2) & 3) * 8 + ((key >> 4) << 2) + (key & 3);
                unsigned short* base = vtc + ((size_t)(bb * H_ + h) * VST + ch) * VCS + slot;
#pragma unroll
                for (int ni = 0; ni < 4; ni++)
#pragma unroll
                    for (int reg = 0; reg < 4; reg++)
                        base[(ni * 16 + quad * 4 + reg) * 40] = bf16u(acc[mi][ni][reg]);
            }
        }
    }
}

__global__ __launch_bounds__(256) void gemm_proj_mfma(
        const unsigned short* __restrict__ A, const unsigned short* __restrict__ W,
        const float* __restrict__ bias, float* __restrict__ out) {
    __shared__ __align__(16) unsigned short As[128 * 32];
    __shared__ __align__(16) unsigned short Bs[128 * 32];
    int tid = threadIdx.x;
    int w = tid >> 6, lane = tid & 63;
    int quad = lane >> 4, l16 = lane & 15;
    int m0 = blockIdx.y * 128;
    int n0 = blockIdx.x * 128;
    int wr = (w >> 1) * 64, wc = (w & 1) * 64;

    int c0 = tid, c1 = tid + 256;
    int a_r0 = min(m0 + (c0 >> 2), M_ - 1), a_c0 = (c0 & 3) * 8;
    int a_r1 = min(m0 + (c1 >> 2), M_ - 1), a_c1 = (c1 & 3) * 8;
    int b_r0 = n0 + (c0 >> 2), b_r1 = n0 + (c1 >> 2);

    f32x4 acc[4][4];
    const f32x4 zero4 = {0.f, 0.f, 0.f, 0.f};
#pragma unroll
    for (int mi = 0; mi < 4; mi++)
#pragma unroll
        for (int ni = 0; ni < 4; ni++) acc[mi][ni] = zero4;

    for (int k0 = 0; k0 < GK; k0 += 32) {
        __syncthreads();
        load_lds16(A + (size_t)a_r0 * GK + k0 + a_c0, &As[w * 512]);
        load_lds16(A + (size_t)a_r1 * GK + k0 + a_c1, &As[2048 + w * 512]);
        load_lds16(W + (size_t)b_r0 * GK + k0 + a_c0, &Bs[w * 512]);
        load_lds16(W + (size_t)b_r1 * GK + k0 + a_c1, &Bs[2048 + w * 512]);
        __syncthreads();
        short8 af[4], bf[4];
#pragma unroll
        for (int mi = 0; mi < 4; mi++)
            af[mi] = *(const short8*)&As[(wr + mi * 16 + l16) * 32 + quad * 8];
#pragma unroll
        for (int ni = 0; ni < 4; ni++)
            bf[ni] = *(const short8*)&Bs[(wc + ni * 16 + l16) * 32 + quad * 8];
#pragma unroll
        for (int mi = 0; mi < 4; mi++)
#pragma unroll
            for (int ni = 0; ni < 4; ni++)
                acc[mi][ni] = __builtin_amdgcn_mfma_f32_16x16x32_bf16(
                    af[mi], bf[ni], acc[mi][ni], 0, 0, 0);
    }

    float bvals[4];
#pragma unroll
    for (int ni = 0; ni < 4; ni++) bvals[ni] = bias[n0 + wc + ni * 16 + l16];
#pragma unroll
    for (int mi = 0; mi < 4; mi++)
#pragma unroll
        for (int reg = 0; reg < 4; reg++) {
            int m = m0 + wr + mi * 16 + quad * 4 + reg;
            if (m < M_) {
                float* row = out + (size_t)m * C_ + n0 + wc;
#pragma unroll
                for (int ni = 0; ni < 4; ni++)
                    row[ni * 16 + l16] = acc[mi][ni][reg] + bvals[ni];
            }
        }
}

// ---------------------------------------------------------------------------
// FUSED attention v8: 32 QUERY ROWS PER WAVE (two l16-groups A/B sharing every
// K- and V-fragment ds_read) -> LDS reads per MFMA halve (R2's top pipe at
// ~54%). Grid 256 blocks = 64 bh x 4 mt of 288 rows; blockIdx = bh + 64*mt so
// blockIdx%8 = h: all 8 b-copies of a bigtab stripe AND all 4 mt-copies of a
// bh's K/V land on the same XCD's L2 (bigtab fetch 156MB -> ~20MB).
// Bias: qgrp A prefetched one tile ahead; qgrp B loaded in-tile (hidden under
// QK_A+PV_A). Per-ks processing keeps s/vf/kf liveness short;
// __launch_bounds__(576,3) caps VGPR at 170 (3-wave SIMD: 3x170 <= 512).
// LDS: Ks 24K + Vs 30K = 54K, 1 block/CU.
// ---------------------------------------------------------------------------
#define RT_ 288   // rows per block (9 waves x 32)

__global__ __launch_bounds__(576, 3) void attn_fused(
        const unsigned short* __restrict__ qg,
        const unsigned short* __restrict__ kg,
        const unsigned short* __restrict__ vtc,
        const unsigned short* __restrict__ bigtab,
        unsigned short* __restrict__ ob) {
    // Ks chunk ch = ct*128 + oct*16 + k16 holds K[key=t*96+ct*16+k16][oct*8..+8]
    // Vs: 3 ks-blocks of [64 dims][40 slots] (32 keys sigma-permuted + 8 pad)
    __shared__ __align__(16) unsigned short Ks[2][6144];   // 24 KB
    __shared__ __align__(16) unsigned short Vs[2][7680];   // 30 KB

    int tid = threadIdx.x;
    int w = tid >> 6, lane = tid & 63;
    int quad = lane >> 4, l16 = lane & 15;

    int lin = blockIdx.x;            // 256 blocks
    int bh = lin & 63;               // blockIdx%8 = bh&7 = h -> XCD co-location
    int mt = lin >> 6;               // 0..3
    int b = bh >> 3, h = bh & 7;

    const unsigned short* qp = qg + (size_t)bh * N_ * HD_;
    const unsigned short* kp = kg + (size_t)bh * N_ * HD_;
    const unsigned short* vp = vtc + (size_t)bh * VST * VCS;

    int qrA = mt * RT_ + w * 32 + l16;           // qgrp A rows (A-layout, l16)
    const unsigned short* btA = bigtab + ((size_t)h * 1152 + qrA) * 1056 + quad * 4;
    const unsigned short* btB = btA + (size_t)16 * 1056;

    // Q fragments for both query groups
    short8 qfA[2], qfB[2];
    {
        int rowA = min(qrA, N_ - 1);
        int rowB = min(qrA + 16, N_ - 1);
        qfA[0] = *(const short8*)(qp + (size_t)rowA * HD_ + quad * 8);
        qfA[1] = *(const short8*)(qp + (size_t)rowA * HD_ + 32 + quad * 8);
        qfB[0] = *(const short8*)(qp + (size_t)rowB * HD_ + quad * 8);
        qfB[1] = *(const short8*)(qp + (size_t)rowB * HD_ + 32 + quad * 8);
    }

    f32x4 oA[4], oB[4], lA, lB;
    const f32x4 zero4 = {0.f, 0.f, 0.f, 0.f};
#pragma unroll
    for (int g2 = 0; g2 < 4; g2++) { oA[g2] = zero4; oB[g2] = zero4; }
    lA = zero4; lB = zero4;
    short8 ones;
    {
        short one_bf = (short)0x3F80;
#pragma unroll
        for (int j = 0; j < 8; j++) ones[j] = one_bf;
    }

    // balanced staging: 27 64-chunk blocks (12 K + 15 V), 3 per wave.
    auto stage = [&](int t, int buf) {
#pragma unroll
        for (int r2 = 0; r2 < 3; r2++) {
            int cb = w * 3 + r2;                 // 0..26, uniform per wave
            if (cb < 12) {
                int ch = cb * 64 + lane;
                int ct = ch >> 7, rem = ch & 127;
                int oct = rem >> 4, k16 = rem & 15;
                int key = min(t * 96 + ct * 16 + k16, N_ - 1);
                load_lds16(kp + (size_t)key * HD_ + oct * 8, &Ks[buf][cb * 512]);
            } else {
                int vb = cb - 12;
                load_lds16(vp + (size_t)t * 3 * VCS + (size_t)(vb * 64 + lane) * 8,
                           &Vs[buf][vb * 512]);
            }
        }
    };

    // bias: qgrp A prefetched one tile ahead (6 us4); qgrp B loaded in-tile.
    us4 bAc[6], bAn[6];
#pragma unroll
    for (int i = 0; i < 6; i++)
        bAn[i] = *(const us4*)(btA + (i >> 1) * 32 + (i & 1) * 16);
    stage(0, 0);

#pragma unroll 1
    for (int t = 0; t < 11; t++) {
        int buf = t & 1;
        __syncthreads();                  // Ks/Vs[buf] ready (vmcnt drained)

#pragma unroll
        for (int i = 0; i < 6; i++) bAc[i] = bAn[i];
        us4 bB[6];
        {
            const unsigned short* btp = btB + t * 96;
#pragma unroll
            for (int i = 0; i < 6; i++)
                bB[i] = *(const us4*)(btp + (i >> 1) * 32 + (i & 1) * 16);
        }
        if (t < 10) {
            const unsigned short* btp = btA + (t + 1) * 96;
#pragma unroll
            for (int i = 0; i < 6; i++)
                bAn[i] = *(const us4*)(btp + (i >> 1) * 32 + (i & 1) * 16);
            stage(t + 1, buf ^ 1);
        }

        // ---- per 32-key step: QK (both grps, kf shared), softmax+PV A, B ----
#pragma unroll
        for (int ks = 0; ks < 3; ks++) {
            f32x4 sA[2], sB[2];
#pragma unroll
            for (int ctl = 0; ctl < 2; ctl++) {
                int ct = ks * 2 + ctl;
                short8 kf0 = *(const short8*)&Ks[buf][(ct * 128 + quad * 16 + l16) * 8];
                short8 kf1 = *(const short8*)&Ks[buf][(ct * 128 + (4 + quad) * 16 + l16) * 8];
                sA[ctl] = __builtin_amdgcn_mfma_f32_16x16x32_bf16(kf0, qfA[0], zero4, 0, 0, 0);
                sA[ctl] = __builtin_amdgcn_mfma_f32_16x16x32_bf16(kf1, qfA[1], sA[ctl], 0, 0, 0);
                sB[ctl] = __builtin_amdgcn_mfma_f32_16x16x32_bf16(kf0, qfB[0], zero4, 0, 0, 0);
                sB[ctl] = __builtin_amdgcn_mfma_f32_16x16x32_bf16(kf1, qfB[1], sB[ctl], 0, 0, 0);
            }
            // V fragments read once, shared by both query groups
            const unsigned short* vcp = &Vs[buf][ks * 2560 + quad * 8];
            short8 vf[4];
#pragma unroll
            for (int g2 = 0; g2 < 4; g2++)
                vf[g2] = *(const short8*)(vcp + (g2 * 16 + l16) * 40);

            // softmax + PV, group A
            short8 pfA;
#pragma unroll
            for (int e = 0; e < 8; e++) {
                int par = e >> 2, r = e & 3;
                float bia = h2f(bAc[ks * 2 + par][r]);
                pfA[e] = (short)bf16u(fexp2(sA[par][r] + bia));
            }
            __builtin_amdgcn_s_setprio(1);
#pragma unroll
            for (int g2 = 0; g2 < 4; g2++)
                oA[g2] = __builtin_amdgcn_mfma_f32_16x16x32_bf16(pfA, vf[g2], oA[g2], 0, 0, 0);
            lA = __builtin_amdgcn_mfma_f32_16x16x32_bf16(pfA, ones, lA, 0, 0, 0);
            __builtin_amdgcn_s_setprio(0);

            // softmax + PV, group B
            short8 pfB;
#pragma unroll
            for (int e = 0; e < 8; e++) {
                int par = e >> 2, r = e & 3;
                float bia = h2f(bB[ks * 2 + par][r]);
                pfB[e] = (short)bf16u(fexp2(sB[par][r] + bia));
            }
            __builtin_amdgcn_s_setprio(1);
#pragma unroll
            for (int g2 = 0; g2 < 4; g2++)
                oB[g2] = __builtin_amdgcn_mfma_f32_16x16x32_bf16(pfB, vf[g2], oB[g2], 0, 0, 0);
            lB = __builtin_amdgcn_mfma_f32_16x16x32_bf16(pfB, ones, lB, 0, 0, 0);
            __builtin_amdgcn_s_setprio(0);
        }
    }

    // ---- epilogue: o/l -> ob bf16 (C-layout rows = query; pad rows skip) ----
#pragma unroll
    for (int grp = 0; grp < 2; grp++) {
        int rbase = mt * RT_ + w * 32 + grp * 16 + quad * 4;
        const f32x4* oX = grp ? oB : oA;
        const f32x4& lX = grp ? lB : lA;
#pragma unroll
        for (int reg = 0; reg < 4; reg++) {
            int r = rbase + reg;
            if (r < N_) {
                float inv = 1.0f / lX[reg];
                unsigned short* orow = ob + ((size_t)b * N_ + r) * C_ + h * HD_ + l16;
#pragma unroll
                for (int g2 = 0; g2 < 4; g2++)
                    orow[g2 * 16] = bf16u(oX[g2][reg] * inv);
            }
        }
    }
}

// ---------------------------------------------------------------------------
extern "C" void kernel_launch(void* const* d_in, const int* in_sizes, int n_in,
                              void* d_out, int out_size, void* d_ws, size_t ws_size,
                              hipStream_t stream) {
    const float* x      = (const float*)d_in[0];
    const float* qkv_w  = (const float*)d_in[1];
    const float* proj_w = (const float*)d_in[2];
    const float* proj_b = (const float*)d_in[3];
    const float* wg_w   = (const float*)d_in[4];
    const float* wg_b   = (const float*)d_in[5];
    float* out = (float*)d_out;

    const size_t per = PER_;
    char* ws = (char*)d_ws;
    unsigned short* bigtab = (unsigned short*)ws;                   // 19,464,192 B
    unsigned short* xb     = bigtab + (size_t)8 * 1152 * 1056;      //  8,396,800 B
    unsigned short* wqkvb  = xb + per;                              //  1,572,864 B
    unsigned short* wprjb  = wqkvb + (size_t)SZ_QKVW;               //    524,288 B
    unsigned short* qb     = wprjb + (size_t)SZ_PRJW;               //  8,396,800 B
    unsigned short* kb     = qb + per;                              //  8,396,800 B
    unsigned short* vtc    = kb + per;                              // 11,796,480 B
    unsigned short* ob     = vtc + (size_t)64 * VST * VCS;          //  8,396,800 B

    prep_kernel<<<EXP_BLKS + CAST_BLKS, 256, 0, stream>>>(x, qkv_w, proj_w, wg_w, wg_b,
                                                          xb, wqkvb, wprjb, bigtab);
    gemm_qkv_mfma<<<dim3(12, 65), 256, 0, stream>>>(xb, wqkvb, qb, kb, vtc);
    attn_fused<<<256, 576, 0, stream>>>(qb, kb, vtc, bigtab, ob);
    gemm_proj_mfma<<<dim3(4, 65), 256, 0, stream>>>(ob, wprjb, proj_b, out);
}

// Round 4
// 182.168 us; speedup vs baseline: 1.2614x; 1.0164x over previous
//
#include <hip/hip_runtime.h>
#include <hip/hip_bf16.h>
#include <hip/hip_fp16.h>
#include <math.h>

#define B_  8
#define N_  1025
#define C_  512
#define H_  8
#define HD_ 64
#define M_  (B_ * N_)   // 8200
#define VCS 2560        // shorts per vtc chunk-block: 64 dims * 40 (32 keys + 8 pad)
#define VST 36          // vtc chunk-blocks per bh (33 used)

typedef __attribute__((ext_vector_type(8))) short short8;
typedef __attribute__((ext_vector_type(4))) float f32x4;
typedef __attribute__((ext_vector_type(4))) unsigned short us4;

__device__ inline unsigned short bf16u(float x) {
    __hip_bfloat16 t = __float2bfloat16(x);
    return *(unsigned short*)&t;
}
__device__ inline float fexp2(float x) {   // 2^x via v_exp_f32
    float r;
    asm("v_exp_f32 %0, %1" : "=v"(r) : "v"(x));
    return r;
}
__device__ inline float h2f(unsigned short u) {
    __half_raw hr; hr.x = u;
    return __half2float(__half(hr));
}
__device__ inline void load_lds16(const void* g, void* l) {
    __builtin_amdgcn_global_load_lds(
        (const __attribute__((address_space(1))) unsigned int*)g,
        (__attribute__((address_space(3))) unsigned int*)l, 16, 0, 0);
}

// ---------------------------------------------------------------------------
// Fused prep:
//   blocks [0,256): bigtab expansion. R3 version burned ~160 libm
//   transcendental calls PER THREAD (4 MLP evals x 8k x 5 calls). X(a,k) and
//   Y(b,k) share one 256-entry sin/cos table -> compute it once per block
//   (2 libcalls/thread), then each eval is 32 FMAs. powf -> constant table.
//   blocks [256, ...): f32 -> bf16 casts of x / qkv_w / proj_w.
// ---------------------------------------------------------------------------
#define PER_ ((size_t)B_ * H_ * N_ * HD_)      // 4,198,400
#define SZ_QKVW (3 * C_ * C_)
#define SZ_PRJW (C_ * C_)
#define CAST_BLKS ((4198400 + 786432 + 262144) / 4 / 256)   // 5124
#define EXP_BLKS 256

__global__ void prep_kernel(const float* __restrict__ x,
                            const float* __restrict__ qkv_w,
                            const float* __restrict__ proj_w,
                            const float* __restrict__ wg_w,
                            const float* __restrict__ wg_b,
                            unsigned short* __restrict__ xb,
                            unsigned short* __restrict__ wqkvb,
                            unsigned short* __restrict__ wprjb,
                            unsigned short* __restrict__ big) {
    __shared__ float tl[1024];
    __shared__ float sT[256], cT[256];
    int blk = blockIdx.x;
    int tid = threadIdx.x;
    if (blk < EXP_BLKS) {
        int h = blk >> 5, rs = blk & 31;
        const float* w = wg_w + h * 64;
        if (tid < 256) {
            const float fr[8] = {1.0f, 0.421696503f, 0.177827941f, 0.074989421f,
                                 0.031622777f, 0.013335214f, 0.005623413f, 0.002371374f};
            int a = tid >> 3, k = tid & 7;
            float dxv = logf(fmaxf((float)a * (1.0f / 33.0f), 0.001f));
            float ang = 100.0f * dxv * fr[k];
            sT[tid] = sinf(ang);
            cT[tid] = cosf(ang);
        }
        __syncthreads();
        float wb = wg_b[h];
        float wtail = 0.f;
#pragma unroll
        for (int k = 0; k < 8; k++) wtail += w[48 + k] + w[56 + k];
#pragma unroll 1
        for (int e = tid; e < 1024; e += 256) {
            int a = e >> 5, b = e & 31;
            float acc = wb + wtail;
#pragma unroll
            for (int k = 0; k < 8; k++) {
                acc += w[k]      * sT[a * 8 + k];
                acc += w[8 + k]  * sT[b * 8 + k];
                acc += w[32 + k] * cT[a * 8 + k];
                acc += w[40 + k] * cT[b * 8 + k];
            }
            tl[e] = log2f(fmaxf(fmaxf(acc, 0.0f), 1e-6f));
        }
        __syncthreads();
        int rbase = rs * 36;
#pragma unroll 1
        for (int e8 = tid; e8 < 36 * 132; e8 += 256) {
            int rr = e8 / 132;
            int cg = e8 - rr * 132;
            int r = rbase + rr;
            int c0 = cg * 8;
            int i = min(r, 1024) - 1;
            int ix = i >> 5, iy = i & 31;
            unsigned short o8[8];
#pragma unroll
            for (int e = 0; e < 8; e++) {
                int c = c0 + e;
                float v;
                if (r == 0 || c == 0) v = 0.f;
                else if (c > 1024)    v = -60000.f;
                else {
                    int j = c - 1;
                    int da = __sad(ix, j >> 5, 0u);
                    int db = __sad(iy, j & 31, 0u);
                    v = tl[da * 32 + db];
                }
                __half hv = __float2half(v);
                o8[e] = *(unsigned short*)&hv;
            }
            *(short8*)(big + ((size_t)h * 1152 + r) * 1056 + c0) = *(short8*)o8;
        }
        return;
    }
    long i4 = ((long)(blk - EXP_BLKS) * 256 + tid) * 4;
    const float* src;
    unsigned short* dst;
    long off;
    if (i4 < (long)PER_)                    { src = x;      dst = xb;    off = i4; }
    else if (i4 < (long)PER_ + SZ_QKVW)     { src = qkv_w;  dst = wqkvb; off = i4 - PER_; }
    else                                    { src = proj_w; dst = wprjb; off = i4 - PER_ - SZ_QKVW; }
    float4 v = *(const float4*)(src + off);
    ushort4 p;
    p.x = bf16u(v.x); p.y = bf16u(v.y); p.z = bf16u(v.z); p.w = bf16u(v.w);
    *(ushort4*)(dst + off) = p;
}

// ---------------------------------------------------------------------------
// MFMA GEMM, 128x128 tile, BK=32, 4 waves, NOW 2-PHASE DOUBLE-BUFFERED:
// R3's loop was  barrier -> issue stage -> barrier(vmcnt0!) -> compute,
// exposing the full global->LDS latency 16x per block. Now: one barrier per
// K-step; stage(k+1, buf^1) issued right after it, hidden under the 16 MFMAs
// (T3-minimal, m248v2). LDS 2x16KB = 32KB.
// q scaled by 0.125*log2(e). v scattered with key-slot permutation
//   sigma(k) = ((k>>2)&3)*8 + ((k>>4)<<2) + (k&3), 40-stride dim rows.
// ---------------------------------------------------------------------------
#define GK 512

__global__ __launch_bounds__(256) void gemm_qkv_mfma(
        const unsigned short* __restrict__ A, const unsigned short* __restrict__ W,
        unsigned short* __restrict__ qb, unsigned short* __restrict__ kb,
        unsigned short* __restrict__ vtc) {
    __shared__ __align__(16) unsigned short As[2][128 * 32];
    __shared__ __align__(16) unsigned short Bs[2][128 * 32];
    int tid = threadIdx.x;
    int w = tid >> 6, lane = tid & 63;
    int quad = lane >> 4, l16 = lane & 15;
    int m0 = blockIdx.y * 128;
    int n0 = blockIdx.x * 128;
    int wr = (w >> 1) * 64, wc = (w & 1) * 64;

    int c0 = tid, c1 = tid + 256;
    int a_r0 = min(m0 + (c0 >> 2), M_ - 1), a_c0 = (c0 & 3) * 8;
    int a_r1 = min(m0 + (c1 >> 2), M_ - 1), a_c1 = (c1 & 3) * 8;
    int b_r0 = n0 + (c0 >> 2), b_r1 = n0 + (c1 >> 2);

    int which = n0 >> 9;                       // 0=q 1=k 2=v
    int h = ((n0 + wc) >> 6) & 7;

    f32x4 acc[4][4];
    const f32x4 zero4 = {0.f, 0.f, 0.f, 0.f};
#pragma unroll
    for (int mi = 0; mi < 4; mi++)
#pragma unroll
        for (int ni = 0; ni < 4; ni++) acc[mi][ni] = zero4;

    auto stage = [&](int k0, int buf) {
        load_lds16(A + (size_t)a_r0 * GK + k0 + a_c0, &As[buf][w * 512]);
        load_lds16(A + (size_t)a_r1 * GK + k0 + a_c1, &As[buf][2048 + w * 512]);
        load_lds16(W + (size_t)b_r0 * GK + k0 + a_c0, &Bs[buf][w * 512]);
        load_lds16(W + (size_t)b_r1 * GK + k0 + a_c1, &Bs[buf][2048 + w * 512]);
    };
    stage(0, 0);

    for (int k0 = 0; k0 < GK; k0 += 32) {
        int buf = (k0 >> 5) & 1;
        __syncthreads();                 // buf staged (vmcnt drained); buf^1 free
        if (k0 + 32 < GK) stage(k0 + 32, buf ^ 1);
        short8 af[4], bf[4];
#pragma unroll
        for (int mi = 0; mi < 4; mi++)
            af[mi] = *(const short8*)&As[buf][(wr + mi * 16 + l16) * 32 + quad * 8];
#pragma unroll
        for (int ni = 0; ni < 4; ni++)
            bf[ni] = *(const short8*)&Bs[buf][(wc + ni * 16 + l16) * 32 + quad * 8];
#pragma unroll
        for (int mi = 0; mi < 4; mi++)
#pragma unroll
            for (int ni = 0; ni < 4; ni++)
                acc[mi][ni] = __builtin_amdgcn_mfma_f32_16x16x32_bf16(
                    bf[ni], af[mi], acc[mi][ni], 0, 0, 0);
    }

    if (which < 2) {
        unsigned short* dst = (which == 0) ? qb : kb;
        float sc = (which == 0) ? 0.18033688f : 1.0f;   // 0.125 * log2(e)
#pragma unroll
        for (int mi = 0; mi < 4; mi++) {
            int m = m0 + wr + mi * 16 + l16;
            if (m < M_) {
                int bb = m / N_;
                int i  = m - bb * N_;
                unsigned short* row = dst + ((size_t)(bb * H_ + h) * N_ + i) * HD_;
#pragma unroll
                for (int ni = 0; ni < 4; ni++) {
                    ushort4 pk;
                    pk.x = bf16u(acc[mi][ni][0] * sc);
                    pk.y = bf16u(acc[mi][ni][1] * sc);
                    pk.z = bf16u(acc[mi][ni][2] * sc);
                    pk.w = bf16u(acc[mi][ni][3] * sc);
                    *(ushort4*)(row + ni * 16 + quad * 4) = pk;
                }
            }
        }
    } else {
#pragma unroll
        for (int mi = 0; mi < 4; mi++) {
            int m = m0 + wr + mi * 16 + l16;
            if (m < M_) {
                int bb = m / N_;
                int i  = m - bb * N_;
                int ch = i >> 5, key = i & 31;
                int slot = ((key >> 2) & 3) * 8 + ((key >> 4) << 2) + (key & 3);
                unsigned short* base = vtc + ((size_t)(bb * H_ + h) * VST + ch) * VCS + slot;
#pragma unroll
                for (int ni = 0; ni < 4; ni++)
#pragma unroll
                    for (int reg = 0; reg < 4; reg++)
                        base[(ni * 16 + quad * 4 + reg) * 40] = bf16u(acc[mi][ni][reg]);
            }
        }
    }
}

__global__ __launch_bounds__(256) void gemm_proj_mfma(
        const unsigned short* __restrict__ A, const unsigned short* __restrict__ W,
        const float* __restrict__ bias, float* __restrict__ out) {
    __shared__ __align__(16) unsigned short As[2][128 * 32];
    __shared__ __align__(16) unsigned short Bs[2][128 * 32];
    int tid = threadIdx.x;
    int w = tid >> 6, lane = tid & 63;
    int quad = lane >> 4, l16 = lane & 15;
    int m0 = blockIdx.y * 128;
    int n0 = blockIdx.x * 128;
    int wr = (w >> 1) * 64, wc = (w & 1) * 64;

    int c0 = tid, c1 = tid + 256;
    int a_r0 = min(m0 + (c0 >> 2), M_ - 1), a_c0 = (c0 & 3) * 8;
    int a_r1 = min(m0 + (c1 >> 2), M_ - 1), a_c1 = (c1 & 3) * 8;
    int b_r0 = n0 + (c0 >> 2), b_r1 = n0 + (c1 >> 2);

    f32x4 acc[4][4];
    const f32x4 zero4 = {0.f, 0.f, 0.f, 0.f};
#pragma unroll
    for (int mi = 0; mi < 4; mi++)
#pragma unroll
        for (int ni = 0; ni < 4; ni++) acc[mi][ni] = zero4;

    auto stage = [&](int k0, int buf) {
        load_lds16(A + (size_t)a_r0 * GK + k0 + a_c0, &As[buf][w * 512]);
        load_lds16(A + (size_t)a_r1 * GK + k0 + a_c1, &As[buf][2048 + w * 512]);
        load_lds16(W + (size_t)b_r0 * GK + k0 + a_c0, &Bs[buf][w * 512]);
        load_lds16(W + (size_t)b_r1 * GK + k0 + a_c1, &Bs[buf][2048 + w * 512]);
    };
    stage(0, 0);

    for (int k0 = 0; k0 < GK; k0 += 32) {
        int buf = (k0 >> 5) & 1;
        __syncthreads();
        if (k0 + 32 < GK) stage(k0 + 32, buf ^ 1);
        short8 af[4], bf[4];
#pragma unroll
        for (int mi = 0; mi < 4; mi++)
            af[mi] = *(const short8*)&As[buf][(wr + mi * 16 + l16) * 32 + quad * 8];
#pragma unroll
        for (int ni = 0; ni < 4; ni++)
            bf[ni] = *(const short8*)&Bs[buf][(wc + ni * 16 + l16) * 32 + quad * 8];
#pragma unroll
        for (int mi = 0; mi < 4; mi++)
#pragma unroll
            for (int ni = 0; ni < 4; ni++)
                acc[mi][ni] = __builtin_amdgcn_mfma_f32_16x16x32_bf16(
                    af[mi], bf[ni], acc[mi][ni], 0, 0, 0);
    }

    float bvals[4];
#pragma unroll
    for (int ni = 0; ni < 4; ni++) bvals[ni] = bias[n0 + wc + ni * 16 + l16];
#pragma unroll
    for (int mi = 0; mi < 4; mi++)
#pragma unroll
        for (int reg = 0; reg < 4; reg++) {
            int m = m0 + wr + mi * 16 + quad * 4 + reg;
            if (m < M_) {
                float* row = out + (size_t)m * C_ + n0 + wc;
#pragma unroll
                for (int ni = 0; ni < 4; ni++)
                    row[ni * 16 + l16] = acc[mi][ni][reg] + bvals[ni];
            }
        }
}

// ---------------------------------------------------------------------------
// FUSED attention v8 (UNCHANGED from R3 — isolate GEMM/prep changes):
// 32 query rows per wave (two l16-groups sharing every K/V ds_read), grid
// 256 = 64 bh x 4 mt, blockIdx%8 = h for XCD L2 co-location. Swapped-QK
// registers-only softmax; bias A prefetched one tile ahead, B in-tile.
// ---------------------------------------------------------------------------
#define RT_ 288   // rows per block (9 waves x 32)

__global__ __launch_bounds__(576, 3) void attn_fused(
        const unsigned short* __restrict__ qg,
        const unsigned short* __restrict__ kg,
        const unsigned short* __restrict__ vtc,
        const unsigned short* __restrict__ bigtab,
        unsigned short* __restrict__ ob) {
    // Ks chunk ch = ct*128 + oct*16 + k16 holds K[key=t*96+ct*16+k16][oct*8..+8]
    // Vs: 3 ks-blocks of [64 dims][40 slots] (32 keys sigma-permuted + 8 pad)
    __shared__ __align__(16) unsigned short Ks[2][6144];   // 24 KB
    __shared__ __align__(16) unsigned short Vs[2][7680];   // 30 KB

    int tid = threadIdx.x;
    int w = tid >> 6, lane = tid & 63;
    int quad = lane >> 4, l16 = lane & 15;

    int lin = blockIdx.x;            // 256 blocks
    int bh = lin & 63;               // blockIdx%8 = bh&7 = h -> XCD co-location
    int mt = lin >> 6;               // 0..3
    int b = bh >> 3, h = bh & 7;

    const unsigned short* qp = qg + (size_t)bh * N_ * HD_;
    const unsigned short* kp = kg + (size_t)bh * N_ * HD_;
    const unsigned short* vp = vtc + (size_t)bh * VST * VCS;

    int qrA = mt * RT_ + w * 32 + l16;           // qgrp A rows (A-layout, l16)
    const unsigned short* btA = bigtab + ((size_t)h * 1152 + qrA) * 1056 + quad * 4;
    const unsigned short* btB = btA + (size_t)16 * 1056;

    // Q fragments for both query groups
    short8 qfA[2], qfB[2];
    {
        int rowA = min(qrA, N_ - 1);
        int rowB = min(qrA + 16, N_ - 1);
        qfA[0] = *(const short8*)(qp + (size_t)rowA * HD_ + quad * 8);
        qfA[1] = *(const short8*)(qp + (size_t)rowA * HD_ + 32 + quad * 8);
        qfB[0] = *(const short8*)(qp + (size_t)rowB * HD_ + quad * 8);
        qfB[1] = *(const short8*)(qp + (size_t)rowB * HD_ + 32 + quad * 8);
    }

    f32x4 oA[4], oB[4], lA, lB;
    const f32x4 zero4 = {0.f, 0.f, 0.f, 0.f};
#pragma unroll
    for (int g2 = 0; g2 < 4; g2++) { oA[g2] = zero4; oB[g2] = zero4; }
    lA = zero4; lB = zero4;
    short8 ones;
    {
        short one_bf = (short)0x3F80;
#pragma unroll
        for (int j = 0; j < 8; j++) ones[j] = one_bf;
    }

    // balanced staging: 27 64-chunk blocks (12 K + 15 V), 3 per wave.
    auto stage = [&](int t, int buf) {
#pragma unroll
        for (int r2 = 0; r2 < 3; r2++) {
            int cb = w * 3 + r2;                 // 0..26, uniform per wave
            if (cb < 12) {
                int ch = cb * 64 + lane;
                int ct = ch >> 7, rem = ch & 127;
                int oct = rem >> 4, k16 = rem & 15;
                int key = min(t * 96 + ct * 16 + k16, N_ - 1);
                load_lds16(kp + (size_t)key * HD_ + oct * 8, &Ks[buf][cb * 512]);
            } else {
                int vb = cb - 12;
                load_lds16(vp + (size_t)t * 3 * VCS + (size_t)(vb * 64 + lane) * 8,
                           &Vs[buf][vb * 512]);
            }
        }
    };

    // bias: qgrp A prefetched one tile ahead (6 us4); qgrp B loaded in-tile.
    us4 bAc[6], bAn[6];
#pragma unroll
    for (int i = 0; i < 6; i++)
        bAn[i] = *(const us4*)(btA + (i >> 1) * 32 + (i & 1) * 16);
    stage(0, 0);

#pragma unroll 1
    for (int t = 0; t < 11; t++) {
        int buf = t & 1;
        __syncthreads();                  // Ks/Vs[buf] ready (vmcnt drained)

#pragma unroll
        for (int i = 0; i < 6; i++) bAc[i] = bAn[i];
        us4 bB[6];
        {
            const unsigned short* btp = btB + t * 96;
#pragma unroll
            for (int i = 0; i < 6; i++)
                bB[i] = *(const us4*)(btp + (i >> 1) * 32 + (i & 1) * 16);
        }
        if (t < 10) {
            const unsigned short* btp = btA + (t + 1) * 96;
#pragma unroll
            for (int i = 0; i < 6; i++)
                bAn[i] = *(const us4*)(btp + (i >> 1) * 32 + (i & 1) * 16);
            stage(t + 1, buf ^ 1);
        }

        // ---- per 32-key step: QK (both grps, kf shared), softmax+PV A, B ----
#pragma unroll
        for (int ks = 0; ks < 3; ks++) {
            f32x4 sA[2], sB[2];
#pragma unroll
            for (int ctl = 0; ctl < 2; ctl++) {
                int ct = ks * 2 + ctl;
                short8 kf0 = *(const short8*)&Ks[buf][(ct * 128 + quad * 16 + l16) * 8];
                short8 kf1 = *(const short8*)&Ks[buf][(ct * 128 + (4 + quad) * 16 + l16) * 8];
                sA[ctl] = __builtin_amdgcn_mfma_f32_16x16x32_bf16(kf0, qfA[0], zero4, 0, 0, 0);
                sA[ctl] = __builtin_amdgcn_mfma_f32_16x16x32_bf16(kf1, qfA[1], sA[ctl], 0, 0, 0);
                sB[ctl] = __builtin_amdgcn_mfma_f32_16x16x32_bf16(kf0, qfB[0], zero4, 0, 0, 0);
                sB[ctl] = __builtin_amdgcn_mfma_f32_16x16x32_bf16(kf1, qfB[1], sB[ctl], 0, 0, 0);
            }
            // V fragments read once, shared by both query groups
            const unsigned short* vcp = &Vs[buf][ks * 2560 + quad * 8];
            short8 vf[4];
#pragma unroll
            for (int g2 = 0; g2 < 4; g2++)
                vf[g2] = *(const short8*)(vcp + (g2 * 16 + l16) * 40);

            // softmax + PV, group A
            short8 pfA;
#pragma unroll
            for (int e = 0; e < 8; e++) {
                int par = e >> 2, r = e & 3;
                float bia = h2f(bAc[ks * 2 + par][r]);
                pfA[e] = (short)bf16u(fexp2(sA[par][r] + bia));
            }
            __builtin_amdgcn_s_setprio(1);
#pragma unroll
            for (int g2 = 0; g2 < 4; g2++)
                oA[g2] = __builtin_amdgcn_mfma_f32_16x16x32_bf16(pfA, vf[g2], oA[g2], 0, 0, 0);
            lA = __builtin_amdgcn_mfma_f32_16x16x32_bf16(pfA, ones, lA, 0, 0, 0);
            __builtin_amdgcn_s_setprio(0);

            // softmax + PV, group B
            short8 pfB;
#pragma unroll
            for (int e = 0; e < 8; e++) {
                int par = e >> 2, r = e & 3;
                float bia = h2f(bB[ks * 2 + par][r]);
                pfB[e] = (short)bf16u(fexp2(sB[par][r] + bia));
            }
            __builtin_amdgcn_s_setprio(1);
#pragma unroll
            for (int g2 = 0; g2 < 4; g2++)
                oB[g2] = __builtin_amdgcn_mfma_f32_16x16x32_bf16(pfB, vf[g2], oB[g2], 0, 0, 0);
            lB = __builtin_amdgcn_mfma_f32_16x16x32_bf16(pfB, ones, lB, 0, 0, 0);
            __builtin_amdgcn_s_setprio(0);
        }
    }

    // ---- epilogue: o/l -> ob bf16 (C-layout rows = query; pad rows skip) ----
#pragma unroll
    for (int grp = 0; grp < 2; grp++) {
        int rbase = mt * RT_ + w * 32 + grp * 16 + quad * 4;
        const f32x4* oX = grp ? oB : oA;
        const f32x4& lX = grp ? lB : lA;
#pragma unroll
        for (int reg = 0; reg < 4; reg++) {
            int r = rbase + reg;
            if (r < N_) {
                float inv = 1.0f / lX[reg];
                unsigned short* orow = ob + ((size_t)b * N_ + r) * C_ + h * HD_ + l16;
#pragma unroll
                for (int g2 = 0; g2 < 4; g2++)
                    orow[g2 * 16] = bf16u(oX[g2][reg] * inv);
            }
        }
    }
}

// ---------------------------------------------------------------------------
extern "C" void kernel_launch(void* const* d_in, const int* in_sizes, int n_in,
                              void* d_out, int out_size, void* d_ws, size_t ws_size,
                              hipStream_t stream) {
    const float* x      = (const float*)d_in[0];
    const float* qkv_w  = (const float*)d_in[1];
    const float* proj_w = (const float*)d_in[2];
    const float* proj_b = (const float*)d_in[3];
    const float* wg_w   = (const float*)d_in[4];
    const float* wg_b   = (const float*)d_in[5];
    float* out = (float*)d_out;

    const size_t per = PER_;
    char* ws = (char*)d_ws;
    unsigned short* bigtab = (unsigned short*)ws;                   // 19,464,192 B
    unsigned short* xb     = bigtab + (size_t)8 * 1152 * 1056;      //  8,396,800 B
    unsigned short* wqkvb  = xb + per;                              //  1,572,864 B
    unsigned short* wprjb  = wqkvb + (size_t)SZ_QKVW;               //    524,288 B
    unsigned short* qb     = wprjb + (size_t)SZ_PRJW;               //  8,396,800 B
    unsigned short* kb     = qb + per;                              //  8,396,800 B
    unsigned short* vtc    = kb + per;                              // 11,796,480 B
    unsigned short* ob     = vtc + (size_t)64 * VST * VCS;          //  8,396,800 B

    prep_kernel<<<EXP_BLKS + CAST_BLKS, 256, 0, stream>>>(x, qkv_w, proj_w, wg_w, wg_b,
                                                          xb, wqkvb, wprjb, bigtab);
    gemm_qkv_mfma<<<dim3(12, 65), 256, 0, stream>>>(xb, wqkvb, qb, kb, vtc);
    attn_fused<<<256, 576, 0, stream>>>(qb, kb, vtc, bigtab, ob);
    gemm_proj_mfma<<<dim3(4, 65), 256, 0, stream>>>(ob, wprjb, proj_b, out);
}